// Round 7
// baseline (607.706 us; speedup 1.0000x reference)
//
#include <hip/hip_runtime.h>
#include <stdint.h>

// Problem constants (B=4, N=4096, D_MODEL=1024, H=16, Dh=64, K_EIG=16)
#define NTOK   16384          // B*N tokens
#define DM     1024           // d_model (GEMM K)
#define NQKV   3072           // folded output features: [Qf|Kf|VfT]
// Layout: Qf rows 0..1023 (kE*64+d), Kf rows 1024..2047 (kE*64+d),
//         VfT rows 2048..3071 (d*16+kE)  <- V transposed per token: attn PV B-frag
//         is a coalesced half8 load.

typedef __attribute__((ext_vector_type(8))) _Float16 half8;
typedef __attribute__((ext_vector_type(4))) float    float4v;

#define MFMA16 __builtin_amdgcn_mfma_f32_16x16x32_f16
#define BARX()  do{ asm volatile("" ::: "memory"); __builtin_amdgcn_s_barrier(); asm volatile("" ::: "memory"); }while(0)
#define VMCNT(N) asm volatile("s_waitcnt vmcnt(" #N ")" ::: "memory")

__device__ __forceinline__ void async_cp16(const void* g, void* l){
  __builtin_amdgcn_global_load_lds(
      (const __attribute__((address_space(1))) void*)g,
      (__attribute__((address_space(3))) void*)l, 16, 0, 0);
}

// ---------------- x fp32 -> fp16 (16-B stores) ----------------
__global__ void cvt_x_kernel(const float* __restrict__ x, _Float16* __restrict__ xb){
  int i = (blockIdx.x * blockDim.x + threadIdx.x) * 8;
  const int stride = gridDim.x * blockDim.x * 8;
  for(; i < NTOK * DM; i += stride){
    float4v v0 = *(const float4v*)(x + i);
    float4v v1 = *(const float4v*)(x + i + 4);
    half8 o;
    o[0]=(_Float16)v0[0]; o[1]=(_Float16)v0[1]; o[2]=(_Float16)v0[2]; o[3]=(_Float16)v0[3];
    o[4]=(_Float16)v1[0]; o[5]=(_Float16)v1[1]; o[6]=(_Float16)v1[2]; o[7]=(_Float16)v1[3];
    *(half8*)(xb + i) = o;
  }
}

// ---------------- fold E,w into weights (+ fused bias fold + ctr zero) ----------------
// p=0,1 (Q,K): n = p*1024 + ke*64 + dd.  p=2 (V): n = 2048 + dd*16 + ke  (transposed).
__global__ __launch_bounds__(256)
void prep_w_kernel(const float* __restrict__ Wq, const float* __restrict__ Wk,
                   const float* __restrict__ Wv,
                   const float* __restrict__ bq, const float* __restrict__ bk,
                   const float* __restrict__ bv,
                   const float* __restrict__ E,  const float* __restrict__ fw,
                   _Float16* __restrict__ WT,    float* __restrict__ fb,
                   unsigned* __restrict__ ctr){
  __shared__ float Wl[8][1032];            // padded rows
  __shared__ float oT[16][8][65];          // [kE][c][d], pad 65 -> conflict-free
  __shared__ float sEv[256];
  __shared__ float sFw[16];
  const int t  = threadIdx.x;
  const int bx = blockIdx.x;               // 0..383
  const int p  = bx >> 7, rt = bx & 127;   // p in 0..2, rt in 0..127
  const int c0 = rt * 8;
  const float* W = (p == 0) ? Wq : (p == 1) ? Wk : Wv;
  sEv[t] = E[t];
  if(t < 16) sFw[t] = fw[t];
  if(bx == 0 && t < 64) ctr[t] = 0u;       // zero band counters EVERY graph replay

  #pragma unroll
  for(int j = 0; j < 32; ++j){
    const int flat = j * 256 + t;          // 0..8191
    const int row = flat >> 10, col = flat & 1023;
    Wl[row][col] = W[(size_t)(c0 + row) * 1024 + col];
  }
  __syncthreads();

  const int d = t & 63, rg = t >> 6;
  #pragma unroll
  for(int rr = 0; rr < 2; ++rr){
    const int row = rg * 2 + rr;
    float w[16];
    #pragma unroll
    for(int h = 0; h < 16; ++h) w[h] = Wl[row][h * 64 + d];
    #pragma unroll
    for(int ke = 0; ke < 16; ++ke){
      float acc = 0.f;
      #pragma unroll
      for(int h = 0; h < 16; ++h) acc += sEv[h * 16 + ke] * w[h];
      oT[ke][row][d] = acc * sFw[ke];
    }
  }
  __syncthreads();

  #pragma unroll
  for(int k4 = 0; k4 < 4; ++k4){
    const int idx = k4 * 256 + t;          // 0..1023
    const int ke = idx >> 6, dd = idx & 63;
    half8 o;
    #pragma unroll
    for(int c = 0; c < 8; ++c) o[c] = (_Float16)oT[ke][c][dd];
    const int n = (p == 2) ? (2048 + dd * 16 + ke) : (p * 1024 + ke * 64 + dd);
    *(half8*)(WT + (size_t)n * 1024 + c0) = o;
  }

  // fused bias fold: rt==0 blocks handle their p's 1024 outputs
  if(rt == 0){
    const float* b = (p == 0) ? bq : (p == 1) ? bk : bv;
    #pragma unroll
    for(int it = 0; it < 4; ++it){
      const int idx = it * 256 + t;        // 0..1023
      const int ke = idx >> 6, dd = idx & 63;
      float acc = 0.f;
      #pragma unroll
      for(int h = 0; h < 16; ++h) acc += sEv[h * 16 + ke] * b[h * 64 + dd];
      acc *= sFw[ke];
      const int n = (p == 2) ? (2048 + dd * 16 + ke) : (p * 1024 + ke * 64 + dd);
      fb[n] = acc;
    }
  }
}

// ---------------- 256x256 GEMM (r5 core, reverted) + fused per-band attention ----------
// GEMM hot loop: frozen r5 structure (102.5us, MfmaUtil 44%, 0 conflicts, VGPR 104).
// nt-FAST swizzle: a band's 12 n-blocks dispatch consecutively -> bands complete
// progressively; the 12th finisher (atomicAdd==11) runs attention for its 256 tokens
// inline, overlapping remaining gemm blocks (no spin anywhere -> no deadlock; fences
// make C-readback correct regardless of XCD placement).
struct FlagF { static constexpr bool value = false; };
struct FlagT { static constexpr bool value = true; };

__global__ __launch_bounds__(512, 2)
void gemm_qkv_kernel(const _Float16* __restrict__ A,   // [16384][1024] fp16
                     const _Float16* __restrict__ BT,  // [3072][1024] fp16
                     const float* __restrict__ bias,   // [3072] fp32
                     _Float16* C,                      // [16384][3072] fp16 (RW)
                     const float* __restrict__ E,      // [16][16] fp32
                     float* out,                       // [16384][1024] fp32
                     unsigned* ctr){                   // [64] band counters
  extern __shared__ _Float16 lds[];   // 65536 halfs = 128KB
  const int t = threadIdx.x;
  const int lane = t & 63, wv = t >> 6;
  const int l15 = lane & 15, q = lane >> 4;
  const int wr = wv >> 2, wc = wv & 3;           // 2M x 4N waves

  const int bid = blockIdx.x;                    // 0..767
  const int xcd = bid & 7, s = bid >> 3;         // s in 0..95
  const int mtl = s / 12;                        // 0..7  (band-local, SLOW)
  const int nt  = s - mtl * 12;                  // 0..11 (FAST -> band completes early)
  const int band = xcd * 8 + mtl;                // 0..63
  const int m0 = band * 256, n0 = nt * 256;

  const int stR = wv * 16 + (lane >> 3);                 // row in half-tile
  const int stC = (((lane & 7) ^ (lane >> 3)) * 8);      // swizzled col (halfs)
  const int stD = (wv * 128 + lane) * 8;                 // LDS dest (halfs, linear)
  const int qsw = (q * 8) ^ ((l15 & 7) * 8);
  const int aoffb = (wr * 16 + l15) * 64;                // + m*2048 + (qsw ^ kk*32)
  const int boffb = (wc * 16 + l15) * 64;                // + n*4096 + (qsw ^ kk*32)

  auto stgA = [&](_Float16* nb, int kc, int h){
    const _Float16* g = A + (size_t)(m0 + h * 128 + stR) * 1024 + kc + stC;
    _Float16* d = nb + h * 8192 + stD;
    async_cp16(g, d);
    async_cp16(g + 8 * 1024, d + 512);
  };
  auto stgB = [&](_Float16* nb, int kc, int h){
    const _Float16* g = BT + (size_t)(n0 + h * 128 + stR) * 1024 + kc + stC;
    _Float16* d = nb + 16384 + h * 8192 + stD;
    async_cp16(g, d);
    async_cp16(g + 8 * 1024, d + 512);
  };

  float4v acc[8][4];
  #pragma unroll
  for(int m = 0; m < 8; ++m)
    #pragma unroll
    for(int n = 0; n < 4; ++n){ acc[m][n][0]=0.f; acc[m][n][1]=0.f; acc[m][n][2]=0.f; acc[m][n][3]=0.f; }

  // prologue: stage K-tile 0 (stream order B0,B1,A0,A1), one-time drain, sync
  stgB(lds, 0, 0);
  stgB(lds, 0, 1);
  stgA(lds, 0, 0);
  stgA(lds, 0, 1);
  VMCNT(0);
  BARX();

  int kt = 0;
  auto ktile = [&](auto lastc){
    constexpr bool LAST = decltype(lastc)::value;
    const _Float16* pA = lds + (kt & 1) * 32768;
    const _Float16* pB = pA + 16384;
    _Float16* nxt = lds + ((kt + 1) & 1) * 32768;
    const int kn = (kt + 1) * 64;

    half8 a0[4], a1[4], b0[4], b1[4], ah[4];

    // ---- P1: A-low k0 (4) + B-all k0 (4); stage T+1.Bh0; 16 MFMA ----
    #pragma unroll
    for(int m = 0; m < 4; ++m) a0[m] = *(const half8*)(pA + aoffb + m * 2048 + qsw);
    #pragma unroll
    for(int n = 0; n < 4; ++n) b0[n] = *(const half8*)(pB + boffb + n * 4096 + qsw);
    if constexpr(!LAST) stgB(nxt, kn, 0);
    __builtin_amdgcn_s_setprio(1);
    #pragma unroll
    for(int m = 0; m < 4; ++m)
      #pragma unroll
      for(int n = 0; n < 4; ++n)
        acc[m][n] = MFMA16(a0[m], b0[n], acc[m][n], 0, 0, 0);
    __builtin_amdgcn_s_setprio(0);

    // ---- P2: A-low k1 (4) + B-all k1 (4); stage T+1.Bh1; 16 MFMA ----
    #pragma unroll
    for(int m = 0; m < 4; ++m) a1[m] = *(const half8*)(pA + aoffb + m * 2048 + (qsw ^ 32));
    #pragma unroll
    for(int n = 0; n < 4; ++n) b1[n] = *(const half8*)(pB + boffb + n * 4096 + (qsw ^ 32));
    if constexpr(!LAST) stgB(nxt, kn, 1);
    __builtin_amdgcn_s_setprio(1);
    #pragma unroll
    for(int m = 0; m < 4; ++m)
      #pragma unroll
      for(int n = 0; n < 4; ++n)
        acc[m][n] = MFMA16(a1[m], b1[n], acc[m][n], 0, 0, 0);
    __builtin_amdgcn_s_setprio(0);

    // ---- mid: confirm T.Ah1 (counted, never 0 except last tile) ----
    if constexpr(!LAST){ VMCNT(4); } else { VMCNT(0); }
    BARX();

    // ---- P3: A-high k0 (4 reads, b0 reused); stage T+1.Ah0; 16 MFMA ----
    #pragma unroll
    for(int m = 0; m < 4; ++m) ah[m] = *(const half8*)(pA + aoffb + (m + 4) * 2048 + qsw);
    if constexpr(!LAST) stgA(nxt, kn, 0);
    __builtin_amdgcn_s_setprio(1);
    #pragma unroll
    for(int m = 0; m < 4; ++m)
      #pragma unroll
      for(int n = 0; n < 4; ++n)
        acc[m + 4][n] = MFMA16(ah[m], b0[n], acc[m + 4][n], 0, 0, 0);
    __builtin_amdgcn_s_setprio(0);

    // ---- P4: A-high k1 (4 reads, b1 reused); stage T+1.Ah1; 16 MFMA ----
    #pragma unroll
    for(int m = 0; m < 4; ++m) ah[m] = *(const half8*)(pA + aoffb + (m + 4) * 2048 + (qsw ^ 32));
    if constexpr(!LAST) stgA(nxt, kn, 1);
    __builtin_amdgcn_s_setprio(1);
    #pragma unroll
    for(int m = 0; m < 4; ++m)
      #pragma unroll
      for(int n = 0; n < 4; ++n)
        acc[m + 4][n] = MFMA16(ah[m], b1[n], acc[m + 4][n], 0, 0, 0);
    __builtin_amdgcn_s_setprio(0);

    // ---- tile end: confirm T+1.{Bh0,Bh1,Ah0}; T+1.Ah1 stays in flight ----
    if constexpr(!LAST){
      VMCNT(2);
      BARX();
    }
  };

  for(kt = 0; kt < 15; ++kt) ktile(FlagF{});
  ktile(FlagT{});

  // epilogue: bias + fp16 store
  #pragma unroll
  for(int n = 0; n < 4; ++n){
    const int col = n0 + (n * 4 + wc) * 16 + l15;
    const float bs = bias[col];
    #pragma unroll
    for(int m = 0; m < 8; ++m){
      const int rbase = m0 + (m * 2 + wr) * 16 + q * 4;
      #pragma unroll
      for(int r = 0; r < 4; ++r)
        C[(size_t)(rbase + r) * NQKV + col] = (_Float16)(acc[m][n][r] + bs);
    }
  }

  // ---------- band completion: last of 12 finishers runs attention ----------
  __threadfence();                               // release: C stores -> device scope
  __syncthreads();                               // all waves' stores+fences done
  volatile int* flag = (int*)lds;
  if(t == 0){
    unsigned old = atomicAdd(&ctr[band], 1u);    // device-scope (m20)
    flag[0] = (old == 11u) ? 1 : 0;
  }
  __syncthreads();
  if(!flag[0]) return;                           // non-runners exit (CU freed)
  __threadfence();                               // acquire: others' C now readable

  // ---- fused attention: 256 tokens, 8 waves x 32 sequential tokens ----
  // pT/gT double-parity (removes LDS WAR between consecutive tokens -> overlap).
  half8 aE;                                      // E A-frag, token-invariant
  if(q < 2){
    float4v e0 = *(const float4v*)(E + l15 * 16 + q * 8);
    float4v e1 = *(const float4v*)(E + l15 * 16 + q * 8 + 4);
    aE[0]=(_Float16)e0[0]; aE[1]=(_Float16)e0[1]; aE[2]=(_Float16)e0[2]; aE[3]=(_Float16)e0[3];
    aE[4]=(_Float16)e1[0]; aE[5]=(_Float16)e1[1]; aE[6]=(_Float16)e1[2]; aE[7]=(_Float16)e1[3];
  }else{
    aE[0]=(_Float16)0.f; aE[1]=(_Float16)0.f; aE[2]=(_Float16)0.f; aE[3]=(_Float16)0.f;
    aE[4]=(_Float16)0.f; aE[5]=(_Float16)0.f; aE[6]=(_Float16)0.f; aE[7]=(_Float16)0.f;
  }

  _Float16* pT0 = lds + 64 + (wv * 2) * 512;            // [parity][16*32]
  _Float16* gT0 = lds + 64 + 8192 + (wv * 2) * 512;
  #pragma unroll
  for(int par = 0; par < 2; ++par)
    #pragma unroll
    for(int s4 = 0; s4 < 4; ++s4){
      const int idx = s4 * 64 + lane;                   // 0..255
      const int off = (idx >> 4) * 32 + 16 + (idx & 15);
      pT0[par * 512 + off] = (_Float16)0.f;             // upper k-cols zero
      gT0[par * 512 + off] = (_Float16)0.f;
    }

  const int tok0 = band * 256 + wv * 32;
  #pragma unroll 2
  for(int it = 0; it < 32; ++it){
    const int tok = tok0 + it;
    const _Float16* tg = C + (size_t)tok * 3072;
    _Float16* pw = pT0 + (it & 1) * 512;
    _Float16* gw = gT0 + (it & 1) * 512;

    half8 aK0 = *(const half8*)(tg + 1024 + l15 * 64 + q * 8);
    half8 aK1 = *(const half8*)(tg + 1024 + l15 * 64 + 32 + q * 8);
    half8 bQ0 = *(const half8*)(tg + l15 * 64 + q * 8);
    half8 bQ1 = *(const half8*)(tg + l15 * 64 + 32 + q * 8);
    const _Float16* tv = tg + 2048;
    half8 vf[4];
    #pragma unroll
    for(int tt = 0; tt < 4; ++tt)
      vf[tt] = *(const half8*)(tv + (tt * 16 + l15) * 16 + (q & 1) * 8);

    float4v S; S[0]=0.f; S[1]=0.f; S[2]=0.f; S[3]=0.f;
    S = MFMA16(aK0, bQ0, S, 0, 0, 0);
    S = MFMA16(aK1, bQ1, S, 0, 0, 0);

    float v[4];
    #pragma unroll
    for(int r = 0; r < 4; ++r) v[r] = S[r] * 0.125f;
    float mx = fmaxf(fmaxf(v[0], v[1]), fmaxf(v[2], v[3]));
    mx = fmaxf(mx, __shfl_xor(mx, 16));
    mx = fmaxf(mx, __shfl_xor(mx, 32));
    float e[4];
    #pragma unroll
    for(int r = 0; r < 4; ++r) e[r] = __expf(v[r] - mx);
    float sm = (e[0] + e[1]) + (e[2] + e[3]);
    sm += __shfl_xor(sm, 16);
    sm += __shfl_xor(sm, 32);
    const float rs = 1.f / sm;

    #pragma unroll
    for(int r = 0; r < 4; ++r) pw[(q * 4 + r) * 32 + l15] = (_Float16)(e[r] * rs);
    half8 bP = *(const half8*)(pw + l15 * 32 + q * 8);

    float4v G; G[0]=0.f; G[1]=0.f; G[2]=0.f; G[3]=0.f;
    G = MFMA16(aE, bP, G, 0, 0, 0);

    #pragma unroll
    for(int r = 0; r < 4; ++r) gw[(q * 4 + r) * 32 + l15] = (_Float16)G[r];
    half8 aG = *(const half8*)(gw + l15 * 32 + q * 8);

    float* ob = out + (size_t)tok * 1024;
    #pragma unroll
    for(int tt = 0; tt < 4; ++tt){
      float4v O; O[0]=0.f; O[1]=0.f; O[2]=0.f; O[3]=0.f;
      O = MFMA16(aG, vf[tt], O, 0, 0, 0);
      #pragma unroll
      for(int r = 0; r < 4; ++r)
        ob[(q * 4 + r) * 64 + tt * 16 + l15] = O[r];
    }
  }
}

extern "C" void kernel_launch(void* const* d_in, const int* in_sizes, int n_in,
                              void* d_out, int out_size, void* d_ws, size_t ws_size,
                              hipStream_t stream){
  const float* x  = (const float*)d_in[0];
  const float* Wq = (const float*)d_in[1];
  const float* bq = (const float*)d_in[2];
  const float* Wk = (const float*)d_in[3];
  const float* bk = (const float*)d_in[4];
  const float* Wv = (const float*)d_in[5];
  const float* bv = (const float*)d_in[6];
  const float* E  = (const float*)d_in[7];
  const float* fw = (const float*)d_in[8];
  float* out = (float*)d_out;

  // workspace layout (136 MB)
  char* ws = (char*)d_ws;
  _Float16* xb  = (_Float16*)ws;                                  // 32 MB
  _Float16* WT  = (_Float16*)(ws + (size_t)32 * 1024 * 1024);     //  6 MB
  float*    fb  = (float*)   (ws + (size_t)38 * 1024 * 1024);     // 12 KB
  unsigned* ctr = (unsigned*)(ws + (size_t)39 * 1024 * 1024);     // 256 B
  _Float16* QKV = (_Float16*)(ws + (size_t)40 * 1024 * 1024);     // 96 MB

  static bool attr_done = false;
  if(!attr_done){
    hipFuncSetAttribute((const void*)gemm_qkv_kernel,
                        hipFuncAttributeMaxDynamicSharedMemorySize, 131072);
    attr_done = true;
  }

  hipLaunchKernelGGL(cvt_x_kernel, dim3(2048), dim3(256), 0, stream, x, xb);
  hipLaunchKernelGGL(prep_w_kernel, dim3(384), dim3(256), 0, stream,
                     Wq, Wk, Wv, bq, bk, bv, E, fw, WT, fb, ctr);
  hipLaunchKernelGGL(gemm_qkv_kernel, dim3(768), dim3(512), 131072, stream,
                     xb, WT, fb, QKV, E, out, ctr);
}

// Round 8
// 275.341 us; speedup vs baseline: 2.2071x; 2.2071x over previous
//
#include <hip/hip_runtime.h>
#include <stdint.h>

// Problem constants (B=4, N=4096, D_MODEL=1024, H=16, Dh=64, K_EIG=16)
#define NTOK   16384          // B*N tokens
#define DM     1024           // d_model (GEMM K)
#define NQKV   3072           // folded output features: [Qf|Kf|VfT]
// Layout: Qf rows 0..1023 (kE*64+d), Kf rows 1024..2047 (kE*64+d),
//         VfT rows 2048..3071 (d*16+kE)  <- V transposed per token: attn PV B-frag
//         is a coalesced half8 load.

typedef __attribute__((ext_vector_type(8))) _Float16 half8;
typedef __attribute__((ext_vector_type(4))) float    float4v;

#define MFMA16 __builtin_amdgcn_mfma_f32_16x16x32_f16
#define BARX()  do{ asm volatile("" ::: "memory"); __builtin_amdgcn_s_barrier(); asm volatile("" ::: "memory"); }while(0)
#define VMCNT(N) asm volatile("s_waitcnt vmcnt(" #N ")" ::: "memory")

__device__ __forceinline__ void async_cp16(const void* g, void* l){
  __builtin_amdgcn_global_load_lds(
      (const __attribute__((address_space(1))) void*)g,
      (__attribute__((address_space(3))) void*)l, 16, 0, 0);
}

// ---------------- fused startup: cvt_x + prep_w + prep_b in ONE launch ----------------
// blocks [0,384): prep_w   (p = bx>>7, rt = bx&127; W reads direct-from-global, coalesced)
// blocks [384,396): prep_b (12 blocks x 256 = 3072 outputs)
// blocks [396,2444): cvt_x (fp32 -> fp16, 16-B stores, grid-stride)
// All branches independent -> safe fusion; LDS ~34 KB -> 4 blocks/CU.
__global__ __launch_bounds__(256)
void prep_all_kernel(const float* __restrict__ x,  _Float16* __restrict__ xb,
                     const float* __restrict__ Wq, const float* __restrict__ Wk,
                     const float* __restrict__ Wv,
                     const float* __restrict__ bq, const float* __restrict__ bk,
                     const float* __restrict__ bv,
                     const float* __restrict__ E,  const float* __restrict__ fw,
                     _Float16* __restrict__ WT,    float* __restrict__ fb){
  __shared__ float oT[16][8][65];          // [kE][c][d], pad 65 -> conflict-free
  __shared__ float sEv[256];
  __shared__ float sFw[16];
  const int t  = threadIdx.x;
  const int bx = blockIdx.x;

  if(bx >= 396){
    // ---------------- cvt_x ----------------
    int i = ((bx - 396) * 256 + t) * 8;
    const int stride = 2048 * 256 * 8;
    for(; i < NTOK * DM; i += stride){
      float4v v0 = *(const float4v*)(x + i);
      float4v v1 = *(const float4v*)(x + i + 4);
      half8 o;
      o[0]=(_Float16)v0[0]; o[1]=(_Float16)v0[1]; o[2]=(_Float16)v0[2]; o[3]=(_Float16)v0[3];
      o[4]=(_Float16)v1[0]; o[5]=(_Float16)v1[1]; o[6]=(_Float16)v1[2]; o[7]=(_Float16)v1[3];
      *(half8*)(xb + i) = o;
    }
    return;
  }

  if(bx >= 384){
    // ---------------- prep_b ----------------
    const int n = (bx - 384) * 256 + t;    // 0..3071
    const int p = n >> 10;
    int kE, d;
    if(p == 2){ kE = n & 15; d = (n >> 4) & 63; }      // VfT rows: n = 2048 + d*16 + kE
    else      { kE = (n >> 6) & 15; d = n & 63; }
    const float* b = (p == 0) ? bq : (p == 1) ? bk : bv;
    float acc = 0.f;
    #pragma unroll
    for(int h = 0; h < 16; ++h) acc += E[h * 16 + kE] * b[h * 64 + d];
    fb[n] = acc * fw[kE];
    return;
  }

  // ---------------- prep_w ----------------
  // p=0,1 (Q,K): n = p*1024 + ke*64 + dd.  p=2 (V): n = 2048 + dd*16 + ke (transposed).
  const int p  = bx >> 7, rt = bx & 127;   // p in 0..2, rt in 0..127
  const int c0 = rt * 8;
  const float* W = (p == 0) ? Wq : (p == 1) ? Wk : Wv;
  sEv[t] = E[t];
  if(t < 16) sFw[t] = fw[t];
  __syncthreads();

  const int d = t & 63, rg = t >> 6;
  #pragma unroll
  for(int rr = 0; rr < 2; ++rr){
    const int row = rg * 2 + rr;
    float w[16];
    #pragma unroll
    for(int h = 0; h < 16; ++h)            // coalesced: lanes d consecutive per (row,h)
      w[h] = W[(size_t)(c0 + row) * 1024 + h * 64 + d];
    #pragma unroll
    for(int ke = 0; ke < 16; ++ke){
      float acc = 0.f;
      #pragma unroll
      for(int h = 0; h < 16; ++h) acc += sEv[h * 16 + ke] * w[h];
      oT[ke][row][d] = acc * sFw[ke];
    }
  }
  __syncthreads();

  #pragma unroll
  for(int k4 = 0; k4 < 4; ++k4){
    const int idx = k4 * 256 + t;          // 0..1023
    const int ke = idx >> 6, dd = idx & 63;
    half8 o;
    #pragma unroll
    for(int c = 0; c < 8; ++c) o[c] = (_Float16)oT[ke][c][dd];
    const int n = (p == 2) ? (2048 + dd * 16 + ke) : (p * 1024 + ke * 64 + dd);
    *(half8*)(WT + (size_t)n * 1024 + c0) = o;
  }
}

// ---------------- 256x256 GEMM, r5 core (frozen: 102.5us, MfmaUtil 44%, 0 conflicts) ----
// 4-phase/tile by (m-half x kk), counted vmcnt never 0 in loop, m-fast XCD band swizzle.
struct FlagF { static constexpr bool value = false; };
struct FlagT { static constexpr bool value = true; };

__global__ __launch_bounds__(512, 2)
void gemm_qkv_kernel(const _Float16* __restrict__ A,   // [16384][1024] fp16
                     const _Float16* __restrict__ BT,  // [3072][1024] fp16
                     const float* __restrict__ bias,   // [3072] fp32
                     _Float16* __restrict__ C){        // [16384][3072] fp16
  extern __shared__ _Float16 lds[];   // 65536 halfs = 128KB: buf[2] x {A 16384, B 16384}
  const int t = threadIdx.x;
  const int lane = t & 63, wv = t >> 6;
  const int l15 = lane & 15, q = lane >> 4;
  const int wr = wv >> 2, wc = wv & 3;           // 2M x 4N waves

  const int bid = blockIdx.x;
  const int xcd = bid & 7, s = bid >> 3;         // s in 0..95
  const int mt = xcd * 8 + (s & 7);              // 0..63 (m fast -> B-tile L2-hot)
  const int nt = s >> 3;                         // 0..11
  const int m0 = mt * 256, n0 = nt * 256;

  const int stR = wv * 16 + (lane >> 3);                 // row in half-tile
  const int stC = (((lane & 7) ^ (lane >> 3)) * 8);      // swizzled col (halfs)
  const int stD = (wv * 128 + lane) * 8;                 // LDS dest (halfs, linear)
  const int qsw = (q * 8) ^ ((l15 & 7) * 8);
  const int aoffb = (wr * 16 + l15) * 64;                // + m*2048 + (qsw ^ kk*32)
  const int boffb = (wc * 16 + l15) * 64;                // + n*4096 + (qsw ^ kk*32)

  auto stgA = [&](_Float16* nb, int kc, int h){
    const _Float16* g = A + (size_t)(m0 + h * 128 + stR) * 1024 + kc + stC;
    _Float16* d = nb + h * 8192 + stD;
    async_cp16(g, d);
    async_cp16(g + 8 * 1024, d + 512);
  };
  auto stgB = [&](_Float16* nb, int kc, int h){
    const _Float16* g = BT + (size_t)(n0 + h * 128 + stR) * 1024 + kc + stC;
    _Float16* d = nb + 16384 + h * 8192 + stD;
    async_cp16(g, d);
    async_cp16(g + 8 * 1024, d + 512);
  };

  float4v acc[8][4];
  #pragma unroll
  for(int m = 0; m < 8; ++m)
    #pragma unroll
    for(int n = 0; n < 4; ++n){ acc[m][n][0]=0.f; acc[m][n][1]=0.f; acc[m][n][2]=0.f; acc[m][n][3]=0.f; }

  // prologue: stage K-tile 0 (stream order B0,B1,A0,A1), one-time drain, sync
  stgB(lds, 0, 0);
  stgB(lds, 0, 1);
  stgA(lds, 0, 0);
  stgA(lds, 0, 1);
  VMCNT(0);
  BARX();

  int kt = 0;
  auto ktile = [&](auto lastc){
    constexpr bool LAST = decltype(lastc)::value;
    const _Float16* pA = lds + (kt & 1) * 32768;
    const _Float16* pB = pA + 16384;
    _Float16* nxt = lds + ((kt + 1) & 1) * 32768;
    const int kn = (kt + 1) * 64;

    half8 a0[4], a1[4], b0[4], b1[4], ah[4];

    // ---- P1: A-low k0 (4) + B-all k0 (4); stage T+1.Bh0; 16 MFMA ----
    #pragma unroll
    for(int m = 0; m < 4; ++m) a0[m] = *(const half8*)(pA + aoffb + m * 2048 + qsw);
    #pragma unroll
    for(int n = 0; n < 4; ++n) b0[n] = *(const half8*)(pB + boffb + n * 4096 + qsw);
    if constexpr(!LAST) stgB(nxt, kn, 0);
    __builtin_amdgcn_s_setprio(1);
    #pragma unroll
    for(int m = 0; m < 4; ++m)
      #pragma unroll
      for(int n = 0; n < 4; ++n)
        acc[m][n] = MFMA16(a0[m], b0[n], acc[m][n], 0, 0, 0);
    __builtin_amdgcn_s_setprio(0);

    // ---- P2: A-low k1 (4) + B-all k1 (4); stage T+1.Bh1; 16 MFMA ----
    #pragma unroll
    for(int m = 0; m < 4; ++m) a1[m] = *(const half8*)(pA + aoffb + m * 2048 + (qsw ^ 32));
    #pragma unroll
    for(int n = 0; n < 4; ++n) b1[n] = *(const half8*)(pB + boffb + n * 4096 + (qsw ^ 32));
    if constexpr(!LAST) stgB(nxt, kn, 1);
    __builtin_amdgcn_s_setprio(1);
    #pragma unroll
    for(int m = 0; m < 4; ++m)
      #pragma unroll
      for(int n = 0; n < 4; ++n)
        acc[m][n] = MFMA16(a1[m], b1[n], acc[m][n], 0, 0, 0);
    __builtin_amdgcn_s_setprio(0);

    // ---- mid: confirm T.Ah1 (counted, never 0 except last tile) ----
    if constexpr(!LAST){ VMCNT(4); } else { VMCNT(0); }
    BARX();

    // ---- P3: A-high k0 (4 reads, b0 reused); stage T+1.Ah0; 16 MFMA ----
    #pragma unroll
    for(int m = 0; m < 4; ++m) ah[m] = *(const half8*)(pA + aoffb + (m + 4) * 2048 + qsw);
    if constexpr(!LAST) stgA(nxt, kn, 0);
    __builtin_amdgcn_s_setprio(1);
    #pragma unroll
    for(int m = 0; m < 4; ++m)
      #pragma unroll
      for(int n = 0; n < 4; ++n)
        acc[m + 4][n] = MFMA16(ah[m], b0[n], acc[m + 4][n], 0, 0, 0);
    __builtin_amdgcn_s_setprio(0);

    // ---- P4: A-high k1 (4 reads, b1 reused); stage T+1.Ah1; 16 MFMA ----
    #pragma unroll
    for(int m = 0; m < 4; ++m) ah[m] = *(const half8*)(pA + aoffb + (m + 4) * 2048 + (qsw ^ 32));
    if constexpr(!LAST) stgA(nxt, kn, 1);
    __builtin_amdgcn_s_setprio(1);
    #pragma unroll
    for(int m = 0; m < 4; ++m)
      #pragma unroll
      for(int n = 0; n < 4; ++n)
        acc[m + 4][n] = MFMA16(ah[m], b1[n], acc[m + 4][n], 0, 0, 0);
    __builtin_amdgcn_s_setprio(0);

    // ---- tile end: confirm T+1.{Bh0,Bh1,Ah0}; T+1.Ah1 stays in flight ----
    if constexpr(!LAST){
      VMCNT(2);
      BARX();
    }
  };

  for(kt = 0; kt < 15; ++kt) ktile(FlagF{});
  ktile(FlagT{});

  // epilogue: bias + fp16 store
  #pragma unroll
  for(int n = 0; n < 4; ++n){
    const int col = n0 + (n * 4 + wc) * 16 + l15;
    const float bs = bias[col];
    #pragma unroll
    for(int m = 0; m < 8; ++m){
      const int rbase = m0 + (m * 2 + wr) * 16 + q * 4;
      #pragma unroll
      for(int r = 0; r < 4; ++r)
        C[(size_t)(rbase + r) * NQKV + col] = (_Float16)(acc[m][n][r] + bs);
    }
  }
}

// ---------------- per-token spectral attention v4 (frozen, r5-benched) ----------------
__global__ __launch_bounds__(256)
void attn_kernel(const _Float16* __restrict__ QKV,   // [NTOK][3072] fp16
                 const float* __restrict__ E,        // [16][16] fp32
                 float* __restrict__ out){           // [NTOK][1024] fp32
  __shared__ _Float16 pT[4][16 * 32];                // per-wave [l][k], cols 16..31 zero
  __shared__ _Float16 gT[4][16 * 32];                // per-wave [h][l], cols 16..31 zero

  const int t = threadIdx.x, lane = t & 63, wv = t >> 6;
  const int l15 = lane & 15, q = lane >> 4;

  const int tok = blockIdx.x * 4 + wv;
  const _Float16* tg = QKV + (size_t)tok * 3072;

  // ---- issue all global loads up front (latency hides under softmax chain) ----
  half8 aK0 = *(const half8*)(tg + 1024 + l15 * 64 + q * 8);
  half8 aK1 = *(const half8*)(tg + 1024 + l15 * 64 + 32 + q * 8);
  half8 bQ0 = *(const half8*)(tg + l15 * 64 + q * 8);
  half8 bQ1 = *(const half8*)(tg + l15 * 64 + 32 + q * 8);
  const _Float16* tv = tg + 2048;
  half8 vf[4];
  #pragma unroll
  for(int tt = 0; tt < 4; ++tt)
    vf[tt] = *(const half8*)(tv + (tt * 16 + l15) * 16 + (q & 1) * 8);
  half8 aE;
  if(q < 2){
    float4v e0 = *(const float4v*)(E + l15 * 16 + q * 8);
    float4v e1 = *(const float4v*)(E + l15 * 16 + q * 8 + 4);
    aE[0]=(_Float16)e0[0]; aE[1]=(_Float16)e0[1]; aE[2]=(_Float16)e0[2]; aE[3]=(_Float16)e0[3];
    aE[4]=(_Float16)e1[0]; aE[5]=(_Float16)e1[1]; aE[6]=(_Float16)e1[2]; aE[7]=(_Float16)e1[3];
  }else{
    aE[0]=(_Float16)0.f; aE[1]=(_Float16)0.f; aE[2]=(_Float16)0.f; aE[3]=(_Float16)0.f;
    aE[4]=(_Float16)0.f; aE[5]=(_Float16)0.f; aE[6]=(_Float16)0.f; aE[7]=(_Float16)0.f;
  }

  // ---- zero own wave's pT/gT upper halves (per-wave private -> no barrier) ----
  #pragma unroll
  for(int s = 0; s < 4; ++s){
    const int idx = s * 64 + lane;                 // 0..255
    const int off = (idx >> 4) * 32 + 16 + (idx & 15);
    pT[wv][off] = (_Float16)0.f;
    gT[wv][off] = (_Float16)0.f;
  }

  // ---- S^T = Kf Qf^T ----
  float4v S; S[0]=0.f; S[1]=0.f; S[2]=0.f; S[3]=0.f;
  S = MFMA16(aK0, bQ0, S, 0, 0, 0);
  S = MFMA16(aK1, bQ1, S, 0, 0, 0);

  float v[4];
  #pragma unroll
  for(int r = 0; r < 4; ++r) v[r] = S[r] * 0.125f;
  float mx = fmaxf(fmaxf(v[0], v[1]), fmaxf(v[2], v[3]));
  mx = fmaxf(mx, __shfl_xor(mx, 16));
  mx = fmaxf(mx, __shfl_xor(mx, 32));
  float e[4];
  #pragma unroll
  for(int r = 0; r < 4; ++r) e[r] = __expf(v[r] - mx);
  float sm = (e[0] + e[1]) + (e[2] + e[3]);
  sm += __shfl_xor(sm, 16);
  sm += __shfl_xor(sm, 32);
  const float rs = 1.f / sm;

  // ---- P -> pT[l][k] (private), read back as B-frag ----
  _Float16* pw = pT[wv];
  #pragma unroll
  for(int r = 0; r < 4; ++r) pw[(q * 4 + r) * 32 + l15] = (_Float16)(e[r] * rs);
  half8 bP = *(const half8*)(pw + l15 * 32 + q * 8);

  float4v G; G[0]=0.f; G[1]=0.f; G[2]=0.f; G[3]=0.f;
  G = MFMA16(aE, bP, G, 0, 0, 0);

  // ---- G -> gT[h][l] (private), read back as A-frag ----
  _Float16* gw = gT[wv];
  #pragma unroll
  for(int r = 0; r < 4; ++r) gw[(q * 4 + r) * 32 + l15] = (_Float16)G[r];
  half8 aG = *(const half8*)(gw + l15 * 32 + q * 8);

  // ---- out = G @ Vf, B-frags straight from global (vf prefetched) ----
  float* ob = out + (size_t)tok * 1024;
  #pragma unroll
  for(int tt = 0; tt < 4; ++tt){
    float4v O; O[0]=0.f; O[1]=0.f; O[2]=0.f; O[3]=0.f;
    O = MFMA16(aG, vf[tt], O, 0, 0, 0);
    #pragma unroll
    for(int r = 0; r < 4; ++r)
      ob[(q * 4 + r) * 64 + tt * 16 + l15] = O[r];
  }
}

extern "C" void kernel_launch(void* const* d_in, const int* in_sizes, int n_in,
                              void* d_out, int out_size, void* d_ws, size_t ws_size,
                              hipStream_t stream){
  const float* x  = (const float*)d_in[0];
  const float* Wq = (const float*)d_in[1];
  const float* bq = (const float*)d_in[2];
  const float* Wk = (const float*)d_in[3];
  const float* bk = (const float*)d_in[4];
  const float* Wv = (const float*)d_in[5];
  const float* bv = (const float*)d_in[6];
  const float* E  = (const float*)d_in[7];
  const float* fw = (const float*)d_in[8];
  float* out = (float*)d_out;

  // workspace layout (136 MB)
  char* ws = (char*)d_ws;
  _Float16* xb  = (_Float16*)ws;                                  // 32 MB
  _Float16* WT  = (_Float16*)(ws + (size_t)32 * 1024 * 1024);     //  6 MB
  float*    fb  = (float*)   (ws + (size_t)38 * 1024 * 1024);     // 12 KB
  _Float16* QKV = (_Float16*)(ws + (size_t)40 * 1024 * 1024);     // 96 MB

  static bool attr_done = false;
  if(!attr_done){
    hipFuncSetAttribute((const void*)gemm_qkv_kernel,
                        hipFuncAttributeMaxDynamicSharedMemorySize, 131072);
    attr_done = true;
  }

  hipLaunchKernelGGL(prep_all_kernel, dim3(2444), dim3(256), 0, stream,
                     x, xb, Wq, Wk, Wv, bq, bk, bv, E, fw, WT, fb);
  hipLaunchKernelGGL(gemm_qkv_kernel, dim3(768), dim3(512), 131072, stream,
                     xb, WT, fb, QKV);
  hipLaunchKernelGGL(attn_kernel, dim3(NTOK / 4), dim3(256), 0, stream, QKV, E, out);
}